// Round 1
// baseline (2498.537 us; speedup 1.0000x reference)
//
#include <hip/hip_runtime.h>
#include <hip/hip_bf16.h>
#include <stdint.h>

#define BB 64
#define HH 1024
#define VV 50257
#define TT 7
#define GG 3072     // 3*HH
#define NT_V 3142   // ceil(VV/16)
#define NT_G 192    // GG/16
#define NBLK 786    // mega-kernel grid: ceil(NT_V/4) blocks of 4 waves

typedef __attribute__((ext_vector_type(8))) short bf16x8;
typedef __attribute__((ext_vector_type(4))) float f32x4;
typedef unsigned short u16;
typedef unsigned int u32;

__device__ __forceinline__ u16 rne_bf16(float f) {
    union { float f; u32 u; } v; v.f = f;
    u32 u = v.u + 0x7FFFu + ((v.u >> 16) & 1u);
    return (u16)(u >> 16);
}
// split f into hi (truncated bf16) + lo (rne bf16 of residual); hi+lo == f to ~2^-17|f|
__device__ __forceinline__ void split2(float f, u16 &hi, u16 &lo) {
    union { float f; u32 u; } v; v.f = f;
    union { u32 u; float f; } hv; hv.u = v.u & 0xFFFF0000u;
    hi = (u16)(v.u >> 16);
    lo = rne_bf16(f - hv.f);
}

// Packed-plane layouts (bf16 bits, u16):
//   W plane:  idx = ((ct*32 + kb)*64 + lane)*8 + j   lane=(q<<4)|l16; col=ct*16+l16; k=kb*32+q*8+j
//   A plane:  idx = ((kb*4 + mt)*64 + lane)*8 + j    m=mt*16+l16;     k=kb*32+q*8+j

// ================== pack kernel: fp32 W (N x 1024 row-major) -> hi/lo planes ==================
__global__ __launch_bounds__(256) void pack_w_kernel(const float* __restrict__ W, int N,
                                                     u16* __restrict__ hi, u16* __restrict__ lo) {
    __shared__ float lds[16][260];
    const int ct = blockIdx.x, kg = blockIdx.y;      // 16 cols x 256 k per block
    const int t = threadIdx.x;
    {   // phase 1: coalesced global -> LDS
        const int r = t >> 4, c = t & 15;
        const int col = ct * 16 + r;
        const float* src = W + (size_t)col * HH + kg * 256;
#pragma unroll
        for (int i = 0; i < 4; ++i) {
            f32x4 v = (f32x4){0.f, 0.f, 0.f, 0.f};
            if (col < N) v = *(const f32x4*)(src + i * 64 + c * 4);
            int x = i * 64 + c * 4;
            lds[r][x + 0] = v[0]; lds[r][x + 1] = v[1];
            lds[r][x + 2] = v[2]; lds[r][x + 3] = v[3];
        }
    }
    __syncthreads();
#pragma unroll
    for (int rep = 0; rep < 2; ++rep) {
        int o = t + rep * 256;
        int tau = o >> 6, lam = o & 63;
        int q = lam >> 4, rr = lam & 15;
        int kl = tau * 32 + q * 8;
        bf16x8 hv, lv;
#pragma unroll
        for (int j = 0; j < 8; ++j) {
            u16 h, l; split2(lds[rr][kl + j], h, l);
            hv[j] = (short)h; lv[j] = (short)l;
        }
        size_t unit = (size_t)(ct * 32 + kg * 8 + tau) * 64 + lam;   // bf16x8 units
        ((bf16x8*)hi)[unit] = hv;
        ((bf16x8*)lo)[unit] = lv;
    }
}

// ================== packed bf16x3 GEMM body (per-wave job) ==================
__device__ __forceinline__ void gemm_packed(
    const u16* __restrict__ Ahi, const u16* __restrict__ Alo,
    const u16* __restrict__ Bhi, const u16* __restrict__ Blo,
    const float* __restrict__ bias, float* __restrict__ C,
    int ct, int N, size_t ldc)
{
    const int lane = threadIdx.x & 63;
    const int q = lane >> 4, l16 = lane & 15;

    const bf16x8* __restrict__ bh = (const bf16x8*)Bhi + (size_t)ct * 2048 + lane;
    const bf16x8* __restrict__ bl = (const bf16x8*)Blo + (size_t)ct * 2048 + lane;
    const bf16x8* __restrict__ ah = (const bf16x8*)Ahi + lane;
    const bf16x8* __restrict__ al = (const bf16x8*)Alo + lane;

    f32x4 acc[4];
#pragma unroll
    for (int mt = 0; mt < 4; ++mt) acc[mt] = (f32x4){0.f, 0.f, 0.f, 0.f};

#pragma unroll 2
    for (int kb = 0; kb < 32; ++kb) {
        bf16x8 bhv = bh[kb * 64];
        bf16x8 blv = bl[kb * 64];
#pragma unroll
        for (int mt = 0; mt < 4; ++mt) {
            bf16x8 ahv = ah[(kb * 4 + mt) * 64];
            bf16x8 alv = al[(kb * 4 + mt) * 64];
            acc[mt] = __builtin_amdgcn_mfma_f32_16x16x32_bf16(ahv, bhv, acc[mt], 0, 0, 0);
            acc[mt] = __builtin_amdgcn_mfma_f32_16x16x32_bf16(alv, bhv, acc[mt], 0, 0, 0);
            acc[mt] = __builtin_amdgcn_mfma_f32_16x16x32_bf16(ahv, blv, acc[mt], 0, 0, 0);
        }
    }

    const int col = ct * 16 + l16;
    if (col < N) {
        float bv = bias[col];
#pragma unroll
        for (int mt = 0; mt < 4; ++mt)
#pragma unroll
            for (int r = 0; r < 4; ++r)
                C[(size_t)(mt * 16 + q * 4 + r) * ldc + col] = acc[mt][r] + bv;
    }
}

// packed A-plane u16 offset for element (b, k)
__device__ __forceinline__ size_t apack_off(int b, int k) {
    int kb = k >> 5, q = (k >> 3) & 3, joff = k & 7;
    int mt = b >> 4, l16 = b & 15;
    return ((size_t)(kb * 4 + mt) * 64 + (q * 16 + l16)) * 8 + joff;
}

// ================== software grid barrier ==================
// flags[NBLK] + epoch live in workspace, zeroed by init kernel each launch.
// Per-block flag store (release) -> block 0 collects -> epoch broadcast (acquire).
// Bounded spins: a co-residency failure produces wrong results, not a hang.
__device__ __forceinline__ void gsync(int* flags, int* epoch, int gen) {
    __syncthreads();
    if (threadIdx.x == 0) {
        __builtin_amdgcn_fence(__ATOMIC_RELEASE, "agent");
        __hip_atomic_store(&flags[blockIdx.x], gen, __ATOMIC_RELAXED, __HIP_MEMORY_SCOPE_AGENT);
    }
    if (blockIdx.x == 0) {
        for (int i = threadIdx.x; i < NBLK; i += 256) {
            int tries = 0;
            while (__hip_atomic_load(&flags[i], __ATOMIC_RELAXED, __HIP_MEMORY_SCOPE_AGENT) < gen) {
                __builtin_amdgcn_s_sleep(2);
                if (++tries > 1000000) break;
            }
        }
        __syncthreads();
        if (threadIdx.x == 0) {
            __builtin_amdgcn_fence(__ATOMIC_ACQ_REL, "agent");
            __hip_atomic_store(epoch, gen, __ATOMIC_RELAXED, __HIP_MEMORY_SCOPE_AGENT);
        }
    }
    if (threadIdx.x == 0) {
        int tries = 0;
        while (__hip_atomic_load(epoch, __ATOMIC_RELAXED, __HIP_MEMORY_SCOPE_AGENT) < gen) {
            __builtin_amdgcn_s_sleep(2);
            if (++tries > 1000000) break;
        }
        __builtin_amdgcn_fence(__ATOMIC_ACQUIRE, "agent");
    }
    __syncthreads();
}

// ================== init: h = enc[0]; e = relu(emb[target[:,0]]); zero barrier ==================
__global__ void init_p2_kernel(const int* __restrict__ target, const float* __restrict__ enc,
                               const float* __restrict__ emb,
                               float* __restrict__ h, u16* __restrict__ h_hp, u16* __restrict__ h_lp,
                               u16* __restrict__ e_hp, u16* __restrict__ e_lp,
                               int* flags, int* epoch) {
    int b = blockIdx.x;
    if (b == 0) {
        for (int i = threadIdx.x; i < NBLK; i += blockDim.x) flags[i] = 0;
        if (threadIdx.x == 0) *epoch = 0;
    }
    int x0 = target[b * TT];
    for (int k = threadIdx.x; k < HH; k += blockDim.x) {
        size_t po = apack_off(b, k);
        float hv = enc[b * HH + k];
        h[b * HH + k] = hv;
        u16 hh, hl; split2(hv, hh, hl);
        h_hp[po] = hh; h_lp[po] = hl;
        float e = emb[(size_t)x0 * HH + k];
        e = e > 0.f ? e : 0.f;
        u16 eh, el; split2(e, eh, el);
        e_hp[po] = eh; e_lp[po] = el;
    }
}

// ================== persistent mega-kernel: all 7 steps + final log-softmax ==================
__global__ __launch_bounds__(256, 4) void mega_kernel(
    const u16* __restrict__ wih_hi, const u16* __restrict__ wih_lo,
    const u16* __restrict__ whh_hi, const u16* __restrict__ whh_lo,
    const u16* __restrict__ wv_hi,  const u16* __restrict__ wv_lo,
    const float* __restrict__ b_ih, const float* __restrict__ b_hh,
    const float* __restrict__ lin_b, const float* __restrict__ emb,
    u16* __restrict__ e_hp, u16* __restrict__ e_lp,
    u16* __restrict__ h_hp, u16* __restrict__ h_lp,
    float* __restrict__ h, float* __restrict__ gi, float* __restrict__ gh,
    float* __restrict__ row_lse, float* __restrict__ out1, float* __restrict__ out2,
    int* flags, int* epoch)
{
    __shared__ float sm[256], ss[256];
    __shared__ int sbi[256];
    int gen = 0;
    const int gw = blockIdx.x * 4 + (threadIdx.x >> 6);   // global wave id

    for (int t = 0; t < TT; ++t) {
        // ---- phase 1: gate GEMMs (384 wave-jobs) ----
        if (gw < 2 * NT_G) {
            int ct = gw >> 1;
            if ((gw & 1) == 0) gemm_packed(e_hp, e_lp, wih_hi, wih_lo, b_ih, gi, ct, GG, GG);
            else               gemm_packed(h_hp, h_lp, whh_hi, whh_lo, b_hh, gh, ct, GG, GG);
        }
        gsync(flags, epoch, ++gen);

        // ---- phase 2: GRU gating (65536 elems) ----
        {
            int idx = blockIdx.x * 256 + threadIdx.x;
            if (idx < BB * HH) {
                int b = idx >> 10, j = idx & 1023;
                float ir = gi[b * GG + j], iz = gi[b * GG + 1024 + j], in_ = gi[b * GG + 2048 + j];
                float hr = gh[b * GG + j], hz = gh[b * GG + 1024 + j], hn = gh[b * GG + 2048 + j];
                float r = 1.f / (1.f + expf(-(ir + hr)));
                float z = 1.f / (1.f + expf(-(iz + hz)));
                float n = tanhf(in_ + r * hn);
                float hold = h[b * HH + j];
                float hnew = (1.f - z) * n + z * hold;
                h[b * HH + j] = hnew;
                u16 hh2, hl2; split2(hnew, hh2, hl2);
                size_t po = apack_off(b, j);
                h_hp[po] = hh2; h_lp[po] = hl2;
            }
        }
        gsync(flags, epoch, ++gen);

        // ---- phase 3: logits GEMM (3142 wave-jobs over 3144 waves) ----
        if (gw < NT_V)
            gemm_packed(h_hp, h_lp, wv_hi, wv_lo, lin_b, out2 + (size_t)t * VV,
                        gw, VV, (size_t)TT * VV);
        gsync(flags, epoch, ++gen);

        // ---- phase 4: argmax + lse + next-embedding gather (64 blocks) ----
        if (blockIdx.x < BB) {
            const int b = blockIdx.x, tid = threadIdx.x;
            const float* row = out2 + (size_t)b * (TT * (size_t)VV) + (size_t)t * VV;
            float m = -INFINITY, s = 0.f; int bi = 0x7fffffff;
            for (int v = tid; v < VV; v += 256) {
                float x = row[v];
                if (x > m) { s = s * expf(m - x) + 1.f; m = x; bi = v; }
                else       { s += expf(x - m); }
            }
            sm[tid] = m; ss[tid] = s; sbi[tid] = bi;
            __syncthreads();
            for (int off = 128; off > 0; off >>= 1) {
                if (tid < off) {
                    float m1 = sm[tid], s1 = ss[tid]; int b1 = sbi[tid];
                    float m2 = sm[tid + off], s2 = ss[tid + off]; int b2 = sbi[tid + off];
                    float mn = fmaxf(m1, m2);
                    float sn = s1 * expf(m1 - mn) + s2 * expf(m2 - mn);
                    int bn = (m1 > m2) ? b1 : (m2 > m1) ? b2 : min(b1, b2);
                    sm[tid] = mn; ss[tid] = sn; sbi[tid] = bn;
                }
                __syncthreads();
            }
            if (tid == 0) row_lse[b * TT + t] = sm[0] + logf(ss[0]);
            int xi = sbi[0];
            for (int k = tid; k < HH; k += 256) {
                float e = emb[(size_t)xi * HH + k];
                e = e > 0.f ? e : 0.f;
                u16 eh, el; split2(e, eh, el);
                size_t po = apack_off(b, k);
                e_hp[po] = eh; e_lp[po] = el;
            }
        }
        gsync(flags, epoch, ++gen);
    }

    // ---- final phase: log_softmax (448 row-jobs) ----
    if (blockIdx.x < BB * TT) {
        int r = blockIdx.x;
        float lse = row_lse[r];
        const float* src = out2 + (size_t)r * VV;
        float* dst = out1 + (size_t)r * VV;
        const int NF4 = VV / 4;   // 12564
        for (int i = threadIdx.x; i < NF4; i += 256) {
            f32x4 v = *(const f32x4*)(src + i * 4);
            v[0] -= lse; v[1] -= lse; v[2] -= lse; v[3] -= lse;
            *(f32x4*)(dst + i * 4) = v;
        }
        if (threadIdx.x == 0) dst[VV - 1] = src[VV - 1] - lse;
    }
}

// ================== final log_softmax (fallback path only) ==================
__global__ void logsoftmax_kernel(const float* __restrict__ out2, const float* __restrict__ row_lse,
                                  float* __restrict__ out1) {
    int row = blockIdx.x;
    float lse = row_lse[row];
    const float* src = out2 + (size_t)row * VV;
    float* dst = out1 + (size_t)row * VV;
    const int NF4 = VV / 4;   // 12564
    for (int i = threadIdx.x; i < NF4; i += blockDim.x) {
        f32x4 v = *(const f32x4*)(src + i * 4);
        v[0] -= lse; v[1] -= lse; v[2] -= lse; v[3] -= lse;
        *(f32x4*)(dst + i * 4) = v;
    }
    if (threadIdx.x == 0) dst[VV - 1] = src[VV - 1] - lse;
}

// ======================================================================
// =================== round-1 fallback path (unpacked) =================
// ======================================================================
__global__ void init_kernel_fb(const int* __restrict__ target, const float* __restrict__ enc,
                               const float* __restrict__ emb,
                               float* __restrict__ h, u16* __restrict__ h_hi, u16* __restrict__ h_lo,
                               u16* __restrict__ e_hi, u16* __restrict__ e_lo) {
    int b = blockIdx.x;
    int x0 = target[b * TT];
    for (int k = threadIdx.x; k < HH; k += blockDim.x) {
        float hv = enc[b * HH + k];
        h[b * HH + k] = hv;
        u16 hh, hl; split2(hv, hh, hl);
        h_hi[b * HH + k] = hh; h_lo[b * HH + k] = hl;
        float e = emb[(size_t)x0 * HH + k];
        e = e > 0.f ? e : 0.f;
        u16 eh, el; split2(e, eh, el);
        e_hi[b * HH + k] = eh; e_lo[b * HH + k] = el;
    }
}

__device__ __forceinline__ void gemm_body_fb(
    const u16* __restrict__ Ahi, const u16* __restrict__ Alo,
    const float* __restrict__ W, const float* __restrict__ bias,
    float* __restrict__ C, int N, int ldc)
{
    const int wave = threadIdx.x >> 6;
    const int lane = threadIdx.x & 63;
    const int quad = lane >> 4;
    const int l16  = lane & 15;
    const int col  = blockIdx.x * 64 + wave * 16 + l16;
    const int colc = col < N ? col : N - 1;
    const float* __restrict__ Brow = W + (size_t)colc * HH;
    const int koff = quad * 8;
    f32x4 acc[4];
#pragma unroll
    for (int mt = 0; mt < 4; ++mt) acc[mt] = (f32x4){0.f, 0.f, 0.f, 0.f};
    for (int kb = 0; kb < HH; kb += 32) {
        const float* bp = Brow + kb + koff;
        f32x4 bv0 = *(const f32x4*)(bp);
        f32x4 bv1 = *(const f32x4*)(bp + 4);
        bf16x8 bhi, blo;
#pragma unroll
        for (int j = 0; j < 8; ++j) {
            float f = j < 4 ? bv0[j] : bv1[j - 4];
            union { float f; u32 u; } c; c.f = f;
            union { u32 u; float f; } hf; hf.u = c.u & 0xFFFF0000u;
            bhi[j] = (short)(c.u >> 16);
            blo[j] = (short)rne_bf16(f - hf.f);
        }
#pragma unroll
        for (int mt = 0; mt < 4; ++mt) {
            const size_t aoff = (size_t)(mt * 16 + l16) * HH + kb + koff;
            bf16x8 ahi = *(const bf16x8*)(Ahi + aoff);
            bf16x8 alo = *(const bf16x8*)(Alo + aoff);
            acc[mt] = __builtin_amdgcn_mfma_f32_16x16x32_bf16(ahi, bhi, acc[mt], 0, 0, 0);
            acc[mt] = __builtin_amdgcn_mfma_f32_16x16x32_bf16(alo, bhi, acc[mt], 0, 0, 0);
            acc[mt] = __builtin_amdgcn_mfma_f32_16x16x32_bf16(ahi, blo, acc[mt], 0, 0, 0);
        }
    }
    if (col < N) {
        float bv = bias[col];
#pragma unroll
        for (int mt = 0; mt < 4; ++mt)
#pragma unroll
            for (int r = 0; r < 4; ++r)
                C[(size_t)(mt * 16 + quad * 4 + r) * ldc + col] = acc[mt][r] + bv;
    }
}

__global__ __launch_bounds__(256) void gemm_gates_kernel_fb(
    const u16* __restrict__ e_hi, const u16* __restrict__ e_lo,
    const u16* __restrict__ h_hi, const u16* __restrict__ h_lo,
    const float* __restrict__ w_ih, const float* __restrict__ w_hh,
    const float* __restrict__ b_ih, const float* __restrict__ b_hh,
    float* __restrict__ gi, float* __restrict__ gh)
{
    if (blockIdx.y == 0) gemm_body_fb(e_hi, e_lo, w_ih, b_ih, gi, GG, GG);
    else                 gemm_body_fb(h_hi, h_lo, w_hh, b_hh, gh, GG, GG);
}

__global__ __launch_bounds__(256) void gemm_logits_kernel_fb(
    const u16* __restrict__ h_hi, const u16* __restrict__ h_lo,
    const float* __restrict__ lin_w, const float* __restrict__ lin_b,
    float* __restrict__ out_logits)
{
    gemm_body_fb(h_hi, h_lo, lin_w, lin_b, out_logits, VV, TT * VV);
}

__global__ void gate_kernel_fb(const float* __restrict__ gi, const float* __restrict__ gh,
                               float* __restrict__ h, u16* __restrict__ h_hi, u16* __restrict__ h_lo) {
    int idx = blockIdx.x * blockDim.x + threadIdx.x;
    int b = idx >> 10, j = idx & 1023;
    float ir = gi[b * GG + j], iz = gi[b * GG + 1024 + j], in_ = gi[b * GG + 2048 + j];
    float hr = gh[b * GG + j], hz = gh[b * GG + 1024 + j], hn = gh[b * GG + 2048 + j];
    float r = 1.f / (1.f + expf(-(ir + hr)));
    float z = 1.f / (1.f + expf(-(iz + hz)));
    float n = tanhf(in_ + r * hn);
    float hold = h[b * HH + j];
    float hnew = (1.f - z) * n + z * hold;
    h[b * HH + j] = hnew;
    u16 hh, hl; split2(hnew, hh, hl);
    h_hi[b * HH + j] = hh; h_lo[b * HH + j] = hl;
}

__global__ __launch_bounds__(256) void argmax_kernel_fb(
    const float* __restrict__ logits_t, const float* __restrict__ emb,
    int t, float* __restrict__ row_lse, u16* __restrict__ e_hi, u16* __restrict__ e_lo)
{
    __shared__ float sm[256], ss[256];
    __shared__ int sbi[256];
    int b = blockIdx.x, tid = threadIdx.x;
    const float* row = logits_t + (size_t)b * (TT * (size_t)VV);
    float m = -INFINITY, s = 0.f; int bi = 0x7fffffff;
    for (int v = tid; v < VV; v += 256) {
        float x = row[v];
        if (x > m) { s = s * expf(m - x) + 1.f; m = x; bi = v; }
        else       { s += expf(x - m); }
    }
    sm[tid] = m; ss[tid] = s; sbi[tid] = bi;
    __syncthreads();
    for (int off = 128; off > 0; off >>= 1) {
        if (tid < off) {
            float m1 = sm[tid], s1 = ss[tid]; int b1 = sbi[tid];
            float m2 = sm[tid + off], s2 = ss[tid + off]; int b2 = sbi[tid + off];
            float mn = fmaxf(m1, m2);
            float sn = s1 * expf(m1 - mn) + s2 * expf(m2 - mn);
            int bn = (m1 > m2) ? b1 : (m2 > m1) ? b2 : min(b1, b2);
            sm[tid] = mn; ss[tid] = sn; sbi[tid] = bn;
        }
        __syncthreads();
    }
    if (tid == 0) row_lse[b * TT + t] = sm[0] + logf(ss[0]);
    int xi = sbi[0];
    __syncthreads();
    for (int k = tid; k < HH; k += 256) {
        float e = emb[(size_t)xi * HH + k];
        e = e > 0.f ? e : 0.f;
        u16 eh, el; split2(e, eh, el);
        e_hi[b * HH + k] = eh; e_lo[b * HH + k] = el;
    }
}

// ======================================================================
extern "C" void kernel_launch(void* const* d_in, const int* in_sizes, int n_in,
                              void* d_out, int out_size, void* d_ws, size_t ws_size,
                              hipStream_t stream) {
    const int*   target = (const int*)  d_in[0];
    const float* enc    = (const float*)d_in[1];
    const float* emb    = (const float*)d_in[2];
    const float* w_ih   = (const float*)d_in[3];
    const float* w_hh   = (const float*)d_in[4];
    const float* b_ih   = (const float*)d_in[5];
    const float* b_hh   = (const float*)d_in[6];
    const float* lin_w  = (const float*)d_in[7];
    const float* lin_b  = (const float*)d_in[8];
    float* out1 = (float*)d_out;                       // log_probs  (B,T,V)
    float* out2 = out1 + (size_t)BB * TT * VV;         // decoder_logits (B,T,V)

    const size_t SZ_WV = (size_t)NT_V * 16384;         // u16 per V plane
    const size_t SZ_WG = (size_t)NT_G * 16384;         // u16 per gates plane
    const size_t need = 2 * SZ_WV * 2 + 4 * SZ_WG * 2  // packed W planes (bytes)
                      + BB * HH * 4                    // h
                      + 4 * BB * HH * 2                // packed A planes
                      + 2 * BB * GG * 4                // gi, gh
                      + BB * TT * 4                    // row_lse
                      + (NBLK + 16) * 4 + 4096;        // barrier state + slack

    if (ws_size >= need) {
        char* w = (char*)d_ws;
        u16* wv_hi = (u16*)w;  w += SZ_WV * 2;
        u16* wv_lo = (u16*)w;  w += SZ_WV * 2;
        u16* wih_hi = (u16*)w; w += SZ_WG * 2;
        u16* wih_lo = (u16*)w; w += SZ_WG * 2;
        u16* whh_hi = (u16*)w; w += SZ_WG * 2;
        u16* whh_lo = (u16*)w; w += SZ_WG * 2;
        float* h   = (float*)w; w += BB * HH * 4;
        u16* h_hp  = (u16*)w;  w += BB * HH * 2;
        u16* h_lp  = (u16*)w;  w += BB * HH * 2;
        u16* e_hp  = (u16*)w;  w += BB * HH * 2;
        u16* e_lp  = (u16*)w;  w += BB * HH * 2;
        float* gi  = (float*)w; w += BB * GG * 4;
        float* gh  = (float*)w; w += BB * GG * 4;
        float* row_lse = (float*)w; w += BB * TT * 4;
        int* flags = (int*)w;   w += NBLK * 4;
        int* epoch = (int*)w;

        // one-time packs (independent of recurrence)
        pack_w_kernel<<<dim3(NT_V, 4), 256, 0, stream>>>(lin_w, VV, wv_hi, wv_lo);
        pack_w_kernel<<<dim3(NT_G, 4), 256, 0, stream>>>(w_ih, GG, wih_hi, wih_lo);
        pack_w_kernel<<<dim3(NT_G, 4), 256, 0, stream>>>(w_hh, GG, whh_hi, whh_lo);
        init_p2_kernel<<<BB, 256, 0, stream>>>(target, enc, emb, h, h_hp, h_lp,
                                               e_hp, e_lp, flags, epoch);

        // single persistent kernel for all 7 steps + final log-softmax
        mega_kernel<<<NBLK, 256, 0, stream>>>(
            wih_hi, wih_lo, whh_hi, whh_lo, wv_hi, wv_lo,
            b_ih, b_hh, lin_b, emb,
            e_hp, e_lp, h_hp, h_lp, h, gi, gh,
            row_lse, out1, out2, flags, epoch);
    } else {
        // -------- fallback: round-1 path (~3.6 MB ws) --------
        char* w = (char*)d_ws;
        float* h    = (float*)w;            w += BB * HH * 4;
        u16*   h_hi = (u16*)w;              w += BB * HH * 2;
        u16*   h_lo = (u16*)w;              w += BB * HH * 2;
        u16*   e_hi = (u16*)w;              w += BB * HH * 2;
        u16*   e_lo = (u16*)w;              w += BB * HH * 2;
        float* gi   = (float*)w;            w += BB * GG * 4;
        float* gh   = (float*)w;            w += BB * GG * 4;
        float* row_lse = (float*)w;

        init_kernel_fb<<<BB, 256, 0, stream>>>(target, enc, emb, h, h_hi, h_lo, e_hi, e_lo);
        const int NB_G = GG / 64;
        const int NB_V = (VV + 63) / 64;
        for (int t = 0; t < TT; ++t) {
            gemm_gates_kernel_fb<<<dim3(NB_G, 2), 256, 0, stream>>>(
                e_hi, e_lo, h_hi, h_lo, w_ih, w_hh, b_ih, b_hh, gi, gh);
            gate_kernel_fb<<<(BB * HH) / 256, 256, 0, stream>>>(gi, gh, h, h_hi, h_lo);
            gemm_logits_kernel_fb<<<NB_V, 256, 0, stream>>>(h_hi, h_lo, lin_w, lin_b,
                                                            out2 + (size_t)t * VV);
            argmax_kernel_fb<<<BB, 256, 0, stream>>>(out2 + (size_t)t * VV, emb, t,
                                                     row_lse, e_hi, e_lo);
        }
        logsoftmax_kernel<<<BB * TT, 256, 0, stream>>>(out2, row_lse, out1);
    }
}

// Round 2
// 2293.309 us; speedup vs baseline: 1.0895x; 1.0895x over previous
//
#include <hip/hip_runtime.h>
#include <hip/hip_bf16.h>
#include <stdint.h>

#define BB 64
#define HH 1024
#define VV 50257
#define TT 7
#define GG 3072     // 3*HH
#define NT_V 3142   // ceil(VV/16)
#define NT_G 192    // GG/16

typedef __attribute__((ext_vector_type(8))) short bf16x8;
typedef __attribute__((ext_vector_type(4))) float f32x4;
typedef unsigned short u16;
typedef unsigned int u32;
typedef unsigned long long u64;

__device__ __forceinline__ u16 rne_bf16(float f) {
    union { float f; u32 u; } v; v.f = f;
    u32 u = v.u + 0x7FFFu + ((v.u >> 16) & 1u);
    return (u16)(u >> 16);
}
// split f into hi (truncated bf16) + lo (rne bf16 of residual); hi+lo == f to ~2^-17|f|
__device__ __forceinline__ void split2(float f, u16 &hi, u16 &lo) {
    union { float f; u32 u; } v; v.f = f;
    union { u32 u; float f; } hv; hv.u = v.u & 0xFFFF0000u;
    hi = (u16)(v.u >> 16);
    lo = rne_bf16(f - hv.f);
}
// monotone order-preserving f32 -> u32 key (total order; larger float => larger key)
__device__ __forceinline__ u32 f2key(float f) {
    union { float f; u32 u; } c; c.f = f;
    return (c.u & 0x80000000u) ? ~c.u : (c.u | 0x80000000u);
}

// Packed-plane layouts (bf16 bits, u16):
//   W plane:  idx = ((ct*32 + kb)*64 + lane)*8 + j   lane=(q<<4)|l16; col=ct*16+l16; k=kb*32+q*8+j
//   A plane:  idx = ((kb*4 + mt)*64 + lane)*8 + j    m=mt*16+l16;     k=kb*32+q*8+j

// ================== pack kernel: fp32 W (N x 1024 row-major) -> hi/lo planes ==================
__global__ __launch_bounds__(256) void pack_w_kernel(const float* __restrict__ W, int N,
                                                     u16* __restrict__ hi, u16* __restrict__ lo) {
    __shared__ float lds[16][260];
    const int ct = blockIdx.x, kg = blockIdx.y;      // 16 cols x 256 k per block
    const int t = threadIdx.x;
    {   // phase 1: coalesced global -> LDS
        const int r = t >> 4, c = t & 15;
        const int col = ct * 16 + r;
        const float* src = W + (size_t)col * HH + kg * 256;
#pragma unroll
        for (int i = 0; i < 4; ++i) {
            f32x4 v = (f32x4){0.f, 0.f, 0.f, 0.f};
            if (col < N) v = *(const f32x4*)(src + i * 64 + c * 4);
            int x = i * 64 + c * 4;
            lds[r][x + 0] = v[0]; lds[r][x + 1] = v[1];
            lds[r][x + 2] = v[2]; lds[r][x + 3] = v[3];
        }
    }
    __syncthreads();
#pragma unroll
    for (int rep = 0; rep < 2; ++rep) {
        int o = t + rep * 256;
        int tau = o >> 6, lam = o & 63;
        int q = lam >> 4, rr = lam & 15;
        int kl = tau * 32 + q * 8;
        bf16x8 hv, lv;
#pragma unroll
        for (int j = 0; j < 8; ++j) {
            u16 h, l; split2(lds[rr][kl + j], h, l);
            hv[j] = (short)h; lv[j] = (short)l;
        }
        size_t unit = (size_t)(ct * 32 + kg * 8 + tau) * 64 + lam;   // bf16x8 units
        ((bf16x8*)hi)[unit] = hv;
        ((bf16x8*)lo)[unit] = lv;
    }
}

// ================== packed bf16x3 GEMM body (per-wave job) ==================
// ARGMAX: additionally reduces per-row max over this wave's 16 columns and
// publishes a packed (f32key<<32 | N-col) candidate via optimistic atomicMax.
template<bool ARGMAX>
__device__ __forceinline__ void gemm_packed_t(
    const u16* __restrict__ Ahi, const u16* __restrict__ Alo,
    const u16* __restrict__ Bhi, const u16* __restrict__ Blo,
    const float* __restrict__ bias, float* __restrict__ C,
    int ct, int N, size_t ldc, u64* keys)
{
    const int lane = threadIdx.x & 63;
    const int q = lane >> 4, l16 = lane & 15;

    const bf16x8* __restrict__ bh = (const bf16x8*)Bhi + (size_t)ct * 2048 + lane;
    const bf16x8* __restrict__ bl = (const bf16x8*)Blo + (size_t)ct * 2048 + lane;
    const bf16x8* __restrict__ ah = (const bf16x8*)Ahi + lane;
    const bf16x8* __restrict__ al = (const bf16x8*)Alo + lane;

    f32x4 acc[4];
#pragma unroll
    for (int mt = 0; mt < 4; ++mt) acc[mt] = (f32x4){0.f, 0.f, 0.f, 0.f};

#pragma unroll 2
    for (int kb = 0; kb < 32; ++kb) {
        bf16x8 bhv = bh[kb * 64];
        bf16x8 blv = bl[kb * 64];
#pragma unroll
        for (int mt = 0; mt < 4; ++mt) {
            bf16x8 ahv = ah[(kb * 4 + mt) * 64];
            bf16x8 alv = al[(kb * 4 + mt) * 64];
            acc[mt] = __builtin_amdgcn_mfma_f32_16x16x32_bf16(ahv, bhv, acc[mt], 0, 0, 0);
            acc[mt] = __builtin_amdgcn_mfma_f32_16x16x32_bf16(alv, bhv, acc[mt], 0, 0, 0);
            acc[mt] = __builtin_amdgcn_mfma_f32_16x16x32_bf16(ahv, blv, acc[mt], 0, 0, 0);
        }
    }

    const int col = ct * 16 + l16;
    float bv = 0.f;
    if (col < N) {
        bv = bias[col];
#pragma unroll
        for (int mt = 0; mt < 4; ++mt)
#pragma unroll
            for (int r = 0; r < 4; ++r)
                C[(size_t)(mt * 16 + q * 4 + r) * ldc + col] = acc[mt][r] + bv;
    }

    if (ARGMAX) {
#pragma unroll
        for (int mt = 0; mt < 4; ++mt) {
#pragma unroll
            for (int r = 0; r < 4; ++r) {
                u32 fk = (col < N) ? f2key(acc[mt][r] + bv) : 0u;
                u64 key = ((u64)fk << 32) | (u32)(N - col);   // larger (N-col) => smaller col wins ties
#pragma unroll
                for (int m = 1; m < 16; m <<= 1) {
                    u64 o = __shfl_xor(key, m);
                    key = key > o ? key : o;
                }
                if (l16 == 0) {
                    int row = mt * 16 + q * 4 + r;
                    u64 cur = __hip_atomic_load(&keys[row], __ATOMIC_RELAXED, __HIP_MEMORY_SCOPE_AGENT);
                    if (key > cur) atomicMax(&keys[row], key);   // rare after filter
                }
            }
        }
    }
}

// ================== gates GEMM with A = relu(emb[xi]) read directly (no e planes) ==========
__device__ __forceinline__ void gemm_emb(
    const float* __restrict__ emb, const u64* __restrict__ keys,
    const u16* __restrict__ Bhi, const u16* __restrict__ Blo,
    const float* __restrict__ bias, float* __restrict__ C, int ct)
{
    const int lane = threadIdx.x & 63;
    const int q = lane >> 4, l16 = lane & 15;

    const bf16x8* __restrict__ bh = (const bf16x8*)Bhi + (size_t)ct * 2048 + lane;
    const bf16x8* __restrict__ bl = (const bf16x8*)Blo + (size_t)ct * 2048 + lane;

    const float* ea[4];
#pragma unroll
    for (int mt = 0; mt < 4; ++mt) {
        int xi = VV - (u32)(keys[mt * 16 + l16] & 0xFFFFFFFFull);
        ea[mt] = emb + (size_t)xi * HH + q * 8;
    }

    f32x4 acc[4];
#pragma unroll
    for (int mt = 0; mt < 4; ++mt) acc[mt] = (f32x4){0.f, 0.f, 0.f, 0.f};

#pragma unroll 2
    for (int kb = 0; kb < 32; ++kb) {
        bf16x8 bhv = bh[kb * 64];
        bf16x8 blv = bl[kb * 64];
#pragma unroll
        for (int mt = 0; mt < 4; ++mt) {
            const float* ep = ea[mt] + kb * 32;
            f32x4 v0 = *(const f32x4*)(ep);
            f32x4 v1 = *(const f32x4*)(ep + 4);
            bf16x8 ahv, alv;
#pragma unroll
            for (int j = 0; j < 8; ++j) {
                float f = j < 4 ? v0[j] : v1[j - 4];
                f = f > 0.f ? f : 0.f;               // relu
                u16 h_, l_; split2(f, h_, l_);
                ahv[j] = (short)h_; alv[j] = (short)l_;
            }
            acc[mt] = __builtin_amdgcn_mfma_f32_16x16x32_bf16(ahv, bhv, acc[mt], 0, 0, 0);
            acc[mt] = __builtin_amdgcn_mfma_f32_16x16x32_bf16(alv, bhv, acc[mt], 0, 0, 0);
            acc[mt] = __builtin_amdgcn_mfma_f32_16x16x32_bf16(ahv, blv, acc[mt], 0, 0, 0);
        }
    }

    const int col = ct * 16 + l16;   // ct < NT_G => col < GG always
    float bv = bias[col];
#pragma unroll
    for (int mt = 0; mt < 4; ++mt)
#pragma unroll
        for (int r = 0; r < 4; ++r)
            C[(size_t)(mt * 16 + q * 4 + r) * GG + col] = acc[mt][r] + bv;
}

// packed A-plane u16 offset for element (b, k)
__device__ __forceinline__ size_t apack_off(int b, int k) {
    int kb = k >> 5, q = (k >> 3) & 3, joff = k & 7;
    int mt = b >> 4, l16 = b & 15;
    return ((size_t)(kb * 4 + mt) * 64 + (q * 16 + l16)) * 8 + joff;
}

// ================== init: h = enc[0]; keys[b] encodes target[:,0] ==================
__global__ void init_p_kernel(const int* __restrict__ target, const float* __restrict__ enc,
                              float* __restrict__ h, u16* __restrict__ h_hp, u16* __restrict__ h_lp,
                              u64* __restrict__ keys) {
    int b = blockIdx.x;
    if (threadIdx.x == 0) keys[b] = (u64)(u32)(VV - target[b * TT]);
    for (int k = threadIdx.x; k < HH; k += blockDim.x) {
        size_t po = apack_off(b, k);
        float hv = enc[b * HH + k];
        h[b * HH + k] = hv;
        u16 hh, hl; split2(hv, hh, hl);
        h_hp[po] = hh; h_lp[po] = hl;
    }
}

// ================== per-step GEMM kernels ==================
__global__ __launch_bounds__(64) void gemm_gates_p_kernel(
    const float* __restrict__ emb, const u64* __restrict__ keys,
    const u16* __restrict__ h_hp, const u16* __restrict__ h_lp,
    const u16* __restrict__ wih_hi, const u16* __restrict__ wih_lo,
    const u16* __restrict__ whh_hi, const u16* __restrict__ whh_lo,
    const float* __restrict__ b_ih, const float* __restrict__ b_hh,
    float* __restrict__ gi, float* __restrict__ gh)
{
    int ct = blockIdx.x;
    if (blockIdx.y == 0) gemm_emb(emb, keys, wih_hi, wih_lo, b_ih, gi, ct);
    else                 gemm_packed_t<false>(h_hp, h_lp, whh_hi, whh_lo, b_hh, gh, ct, GG, GG, nullptr);
}

__global__ __launch_bounds__(256) void gemm_logits_p_kernel(
    const u16* __restrict__ h_hp, const u16* __restrict__ h_lp,
    const u16* __restrict__ wv_hi, const u16* __restrict__ wv_lo,
    const float* __restrict__ lin_b, float* __restrict__ out_logits,
    u64* __restrict__ keys)
{
    int ct = blockIdx.x * 4 + (threadIdx.x >> 6);
    if (ct >= NT_V) return;
    gemm_packed_t<true>(h_hp, h_lp, wv_hi, wv_lo, lin_b, out_logits, ct, VV, (size_t)TT * VV, keys);
}

// ================== GRU gating (packed h out) + argmax-key reset ==================
__global__ void gate_p_kernel(const float* __restrict__ gi, const float* __restrict__ gh,
                              float* __restrict__ h, u16* __restrict__ h_hp, u16* __restrict__ h_lp,
                              u64* __restrict__ keys) {
    if (blockIdx.x == 0 && threadIdx.x < BB) keys[threadIdx.x] = 0ull;  // reset before logits atomics
    int idx = blockIdx.x * blockDim.x + threadIdx.x;
    int b = idx >> 10, j = idx & 1023;
    float ir = gi[b * GG + j], iz = gi[b * GG + 1024 + j], in_ = gi[b * GG + 2048 + j];
    float hr = gh[b * GG + j], hz = gh[b * GG + 1024 + j], hn = gh[b * GG + 2048 + j];
    float r = 1.f / (1.f + expf(-(ir + hr)));
    float z = 1.f / (1.f + expf(-(iz + hz)));
    float n = tanhf(in_ + r * hn);
    float hold = h[b * HH + j];
    float hnew = (1.f - z) * n + z * hold;
    h[b * HH + j] = hnew;
    u16 hh, hl; split2(hnew, hh, hl);
    size_t po = apack_off(b, j);
    h_hp[po] = hh; h_lp[po] = hl;
}

// ================== final: lse per row + log_softmax write ==================
__global__ __launch_bounds__(256) void lse_logsoftmax_kernel(
    const float* __restrict__ out2, float* __restrict__ out1)
{
    __shared__ float sm[256], ss[256];
    int row = blockIdx.x, tid = threadIdx.x;
    const float* src = out2 + (size_t)row * VV;
    float* dst = out1 + (size_t)row * VV;

    float m = -INFINITY, s = 0.f;
    for (int v = tid; v < VV; v += 256) {
        float x = src[v];
        if (x > m) { s = s * expf(m - x) + 1.f; m = x; }
        else       { s += expf(x - m); }
    }
    sm[tid] = m; ss[tid] = s;
    __syncthreads();
    for (int off = 128; off > 0; off >>= 1) {
        if (tid < off) {
            float m1 = sm[tid], s1 = ss[tid];
            float m2 = sm[tid + off], s2 = ss[tid + off];
            float mn = fmaxf(m1, m2);
            sm[tid] = mn; ss[tid] = s1 * expf(m1 - mn) + s2 * expf(m2 - mn);
        }
        __syncthreads();
    }
    float lse = sm[0] + logf(ss[0]);

    const int NF4 = VV / 4;   // 12564  (row re-read is L2-warm)
    for (int i = tid; i < NF4; i += 256) {
        f32x4 v = *(const f32x4*)(src + i * 4);
        v[0] -= lse; v[1] -= lse; v[2] -= lse; v[3] -= lse;
        *(f32x4*)(dst + i * 4) = v;
    }
    if (tid == 0) dst[VV - 1] = src[VV - 1] - lse;
}

// ================== final log_softmax (fallback path only) ==================
__global__ void logsoftmax_kernel(const float* __restrict__ out2, const float* __restrict__ row_lse,
                                  float* __restrict__ out1) {
    int row = blockIdx.x;
    float lse = row_lse[row];
    const float* src = out2 + (size_t)row * VV;
    float* dst = out1 + (size_t)row * VV;
    const int NF4 = VV / 4;   // 12564
    for (int i = threadIdx.x; i < NF4; i += blockDim.x) {
        f32x4 v = *(const f32x4*)(src + i * 4);
        v[0] -= lse; v[1] -= lse; v[2] -= lse; v[3] -= lse;
        *(f32x4*)(dst + i * 4) = v;
    }
    if (threadIdx.x == 0) dst[VV - 1] = src[VV - 1] - lse;
}

// ======================================================================
// =================== round-1 fallback path (unpacked) =================
// ======================================================================
__global__ void init_kernel_fb(const int* __restrict__ target, const float* __restrict__ enc,
                               const float* __restrict__ emb,
                               float* __restrict__ h, u16* __restrict__ h_hi, u16* __restrict__ h_lo,
                               u16* __restrict__ e_hi, u16* __restrict__ e_lo) {
    int b = blockIdx.x;
    int x0 = target[b * TT];
    for (int k = threadIdx.x; k < HH; k += blockDim.x) {
        float hv = enc[b * HH + k];
        h[b * HH + k] = hv;
        u16 hh, hl; split2(hv, hh, hl);
        h_hi[b * HH + k] = hh; h_lo[b * HH + k] = hl;
        float e = emb[(size_t)x0 * HH + k];
        e = e > 0.f ? e : 0.f;
        u16 eh, el; split2(e, eh, el);
        e_hi[b * HH + k] = eh; e_lo[b * HH + k] = el;
    }
}

__device__ __forceinline__ void gemm_body_fb(
    const u16* __restrict__ Ahi, const u16* __restrict__ Alo,
    const float* __restrict__ W, const float* __restrict__ bias,
    float* __restrict__ C, int N, int ldc)
{
    const int wave = threadIdx.x >> 6;
    const int lane = threadIdx.x & 63;
    const int quad = lane >> 4;
    const int l16  = lane & 15;
    const int col  = blockIdx.x * 64 + wave * 16 + l16;
    const int colc = col < N ? col : N - 1;
    const float* __restrict__ Brow = W + (size_t)colc * HH;
    const int koff = quad * 8;
    f32x4 acc[4];
#pragma unroll
    for (int mt = 0; mt < 4; ++mt) acc[mt] = (f32x4){0.f, 0.f, 0.f, 0.f};
    for (int kb = 0; kb < HH; kb += 32) {
        const float* bp = Brow + kb + koff;
        f32x4 bv0 = *(const f32x4*)(bp);
        f32x4 bv1 = *(const f32x4*)(bp + 4);
        bf16x8 bhi, blo;
#pragma unroll
        for (int j = 0; j < 8; ++j) {
            float f = j < 4 ? bv0[j] : bv1[j - 4];
            union { float f; u32 u; } c; c.f = f;
            union { u32 u; float f; } hf; hf.u = c.u & 0xFFFF0000u;
            bhi[j] = (short)(c.u >> 16);
            blo[j] = (short)rne_bf16(f - hf.f);
        }
#pragma unroll
        for (int mt = 0; mt < 4; ++mt) {
            const size_t aoff = (size_t)(mt * 16 + l16) * HH + kb + koff;
            bf16x8 ahi = *(const bf16x8*)(Ahi + aoff);
            bf16x8 alo = *(const bf16x8*)(Alo + aoff);
            acc[mt] = __builtin_amdgcn_mfma_f32_16x16x32_bf16(ahi, bhi, acc[mt], 0, 0, 0);
            acc[mt] = __builtin_amdgcn_mfma_f32_16x16x32_bf16(alo, bhi, acc[mt], 0, 0, 0);
            acc[mt] = __builtin_amdgcn_mfma_f32_16x16x32_bf16(ahi, blo, acc[mt], 0, 0, 0);
        }
    }
    if (col < N) {
        float bv = bias[col];
#pragma unroll
        for (int mt = 0; mt < 4; ++mt)
#pragma unroll
            for (int r = 0; r < 4; ++r)
                C[(size_t)(mt * 16 + quad * 4 + r) * ldc + col] = acc[mt][r] + bv;
    }
}

__global__ __launch_bounds__(256) void gemm_gates_kernel_fb(
    const u16* __restrict__ e_hi, const u16* __restrict__ e_lo,
    const u16* __restrict__ h_hi, const u16* __restrict__ h_lo,
    const float* __restrict__ w_ih, const float* __restrict__ w_hh,
    const float* __restrict__ b_ih, const float* __restrict__ b_hh,
    float* __restrict__ gi, float* __restrict__ gh)
{
    if (blockIdx.y == 0) gemm_body_fb(e_hi, e_lo, w_ih, b_ih, gi, GG, GG);
    else                 gemm_body_fb(h_hi, h_lo, w_hh, b_hh, gh, GG, GG);
}

__global__ __launch_bounds__(256) void gemm_logits_kernel_fb(
    const u16* __restrict__ h_hi, const u16* __restrict__ h_lo,
    const float* __restrict__ lin_w, const float* __restrict__ lin_b,
    float* __restrict__ out_logits)
{
    gemm_body_fb(h_hi, h_lo, lin_w, lin_b, out_logits, VV, TT * VV);
}

__global__ void gate_kernel_fb(const float* __restrict__ gi, const float* __restrict__ gh,
                               float* __restrict__ h, u16* __restrict__ h_hi, u16* __restrict__ h_lo) {
    int idx = blockIdx.x * blockDim.x + threadIdx.x;
    int b = idx >> 10, j = idx & 1023;
    float ir = gi[b * GG + j], iz = gi[b * GG + 1024 + j], in_ = gi[b * GG + 2048 + j];
    float hr = gh[b * GG + j], hz = gh[b * GG + 1024 + j], hn = gh[b * GG + 2048 + j];
    float r = 1.f / (1.f + expf(-(ir + hr)));
    float z = 1.f / (1.f + expf(-(iz + hz)));
    float n = tanhf(in_ + r * hn);
    float hold = h[b * HH + j];
    float hnew = (1.f - z) * n + z * hold;
    h[b * HH + j] = hnew;
    u16 hh, hl; split2(hnew, hh, hl);
    h_hi[b * HH + j] = hh; h_lo[b * HH + j] = hl;
}

__global__ __launch_bounds__(256) void argmax_kernel_fb(
    const float* __restrict__ logits_t, const float* __restrict__ emb,
    int t, float* __restrict__ row_lse, u16* __restrict__ e_hi, u16* __restrict__ e_lo)
{
    __shared__ float sm[256], ss[256];
    __shared__ int sbi[256];
    int b = blockIdx.x, tid = threadIdx.x;
    const float* row = logits_t + (size_t)b * (TT * (size_t)VV);
    float m = -INFINITY, s = 0.f; int bi = 0x7fffffff;
    for (int v = tid; v < VV; v += 256) {
        float x = row[v];
        if (x > m) { s = s * expf(m - x) + 1.f; m = x; bi = v; }
        else       { s += expf(x - m); }
    }
    sm[tid] = m; ss[tid] = s; sbi[tid] = bi;
    __syncthreads();
    for (int off = 128; off > 0; off >>= 1) {
        if (tid < off) {
            float m1 = sm[tid], s1 = ss[tid]; int b1 = sbi[tid];
            float m2 = sm[tid + off], s2 = ss[tid + off]; int b2 = sbi[tid + off];
            float mn = fmaxf(m1, m2);
            float sn = s1 * expf(m1 - mn) + s2 * expf(m2 - mn);
            int bn = (m1 > m2) ? b1 : (m2 > m1) ? b2 : min(b1, b2);
            sm[tid] = mn; ss[tid] = sn; sbi[tid] = bn;
        }
        __syncthreads();
    }
    if (tid == 0) row_lse[b * TT + t] = sm[0] + logf(ss[0]);
    int xi = sbi[0];
    __syncthreads();
    for (int k = tid; k < HH; k += 256) {
        float e = emb[(size_t)xi * HH + k];
        e = e > 0.f ? e : 0.f;
        u16 eh, el; split2(e, eh, el);
        e_hi[b * HH + k] = eh; e_lo[b * HH + k] = el;
    }
}

// ======================================================================
extern "C" void kernel_launch(void* const* d_in, const int* in_sizes, int n_in,
                              void* d_out, int out_size, void* d_ws, size_t ws_size,
                              hipStream_t stream) {
    const int*   target = (const int*)  d_in[0];
    const float* enc    = (const float*)d_in[1];
    const float* emb    = (const float*)d_in[2];
    const float* w_ih   = (const float*)d_in[3];
    const float* w_hh   = (const float*)d_in[4];
    const float* b_ih   = (const float*)d_in[5];
    const float* b_hh   = (const float*)d_in[6];
    const float* lin_w  = (const float*)d_in[7];
    const float* lin_b  = (const float*)d_in[8];
    float* out1 = (float*)d_out;                       // log_probs  (B,T,V)
    float* out2 = out1 + (size_t)BB * TT * VV;         // decoder_logits (B,T,V)

    const size_t SZ_WV = (size_t)NT_V * 16384;         // u16 per V plane
    const size_t SZ_WG = (size_t)NT_G * 16384;         // u16 per gates plane
    const size_t need = 2 * SZ_WV * 2 + 4 * SZ_WG * 2  // packed W planes (bytes)
                      + BB * HH * 4                    // h
                      + 2 * BB * HH * 2                // packed h planes
                      + 2 * BB * GG * 4                // gi, gh
                      + BB * 8 + 1024;                 // keys + slack

    if (ws_size >= need) {
        char* w = (char*)d_ws;
        u16* wv_hi = (u16*)w;  w += SZ_WV * 2;
        u16* wv_lo = (u16*)w;  w += SZ_WV * 2;
        u16* wih_hi = (u16*)w; w += SZ_WG * 2;
        u16* wih_lo = (u16*)w; w += SZ_WG * 2;
        u16* whh_hi = (u16*)w; w += SZ_WG * 2;
        u16* whh_lo = (u16*)w; w += SZ_WG * 2;
        float* h   = (float*)w; w += BB * HH * 4;
        u16* h_hp  = (u16*)w;  w += BB * HH * 2;
        u16* h_lp  = (u16*)w;  w += BB * HH * 2;
        float* gi  = (float*)w; w += BB * GG * 4;
        float* gh  = (float*)w; w += BB * GG * 4;
        u64* keys  = (u64*)w;

        // one-time packs
        pack_w_kernel<<<dim3(NT_V, 4), 256, 0, stream>>>(lin_w, VV, wv_hi, wv_lo);
        pack_w_kernel<<<dim3(NT_G, 4), 256, 0, stream>>>(w_ih, GG, wih_hi, wih_lo);
        pack_w_kernel<<<dim3(NT_G, 4), 256, 0, stream>>>(w_hh, GG, whh_hi, whh_lo);
        init_p_kernel<<<BB, 256, 0, stream>>>(target, enc, h, h_hp, h_lp, keys);

        for (int t = 0; t < TT; ++t) {
            // gates GEMM: y==0 reads relu(emb[xi]) directly via keys; y==1 reads packed h
            gemm_gates_p_kernel<<<dim3(NT_G, 2), 64, 0, stream>>>(
                emb, keys, h_hp, h_lp, wih_hi, wih_lo, whh_hi, whh_lo, b_ih, b_hh, gi, gh);
            // GRU gate + pack h; resets keys for this step's argmax
            gate_p_kernel<<<(BB * HH) / 256, 256, 0, stream>>>(gi, gh, h, h_hp, h_lp, keys);
            // logits GEMM with fused in-register argmax (atomicMax on packed keys)
            gemm_logits_p_kernel<<<(NT_V + 3) / 4, 256, 0, stream>>>(
                h_hp, h_lp, wv_hi, wv_lo, lin_b, out2 + (size_t)t * VV, keys);
        }
        lse_logsoftmax_kernel<<<BB * TT, 256, 0, stream>>>(out2, out1);
    } else {
        // -------- fallback: round-1 path (~3.6 MB ws) --------
        char* w = (char*)d_ws;
        float* h    = (float*)w;            w += BB * HH * 4;
        u16*   h_hi = (u16*)w;              w += BB * HH * 2;
        u16*   h_lo = (u16*)w;              w += BB * HH * 2;
        u16*   e_hi = (u16*)w;              w += BB * HH * 2;
        u16*   e_lo = (u16*)w;              w += BB * HH * 2;
        float* gi   = (float*)w;            w += BB * GG * 4;
        float* gh   = (float*)w;            w += BB * GG * 4;
        float* row_lse = (float*)w;

        init_kernel_fb<<<BB, 256, 0, stream>>>(target, enc, emb, h, h_hi, h_lo, e_hi, e_lo);
        const int NB_G = GG / 64;
        const int NB_V = (VV + 63) / 64;
        for (int t = 0; t < TT; ++t) {
            gemm_gates_kernel_fb<<<dim3(NB_G, 2), 256, 0, stream>>>(
                e_hi, e_lo, h_hi, h_lo, w_ih, w_hh, b_ih, b_hh, gi, gh);
            gate_kernel_fb<<<(BB * HH) / 256, 256, 0, stream>>>(gi, gh, h, h_hi, h_lo);
            gemm_logits_kernel_fb<<<NB_V, 256, 0, stream>>>(h_hi, h_lo, lin_w, lin_b,
                                                            out2 + (size_t)t * VV);
            argmax_kernel_fb<<<BB, 256, 0, stream>>>(out2 + (size_t)t * VV, emb, t,
                                                     row_lse, e_hi, e_lo);
        }
        logsoftmax_kernel<<<BB * TT, 256, 0, stream>>>(out2, row_lse, out1);
    }
}

// Round 3
// 1294.290 us; speedup vs baseline: 1.9304x; 1.7719x over previous
//
#include <hip/hip_runtime.h>
#include <hip/hip_bf16.h>
#include <stdint.h>

#define BB 64
#define HH 1024
#define VV 50257
#define TT 7
#define GG 3072     // 3*HH
#define NT_V 3142   // ceil(VV/16)
#define NT_G 192    // GG/16

typedef __attribute__((ext_vector_type(8))) short bf16x8;
typedef __attribute__((ext_vector_type(4))) float f32x4;
typedef unsigned short u16;
typedef unsigned int u32;
typedef unsigned long long u64;

__device__ __forceinline__ u16 rne_bf16(float f) {
    union { float f; u32 u; } v; v.f = f;
    u32 u = v.u + 0x7FFFu + ((v.u >> 16) & 1u);
    return (u16)(u >> 16);
}
// split f into hi (truncated bf16) + lo (rne bf16 of residual); hi+lo == f to ~2^-17|f|
__device__ __forceinline__ void split2(float f, u16 &hi, u16 &lo) {
    union { float f; u32 u; } v; v.f = f;
    union { u32 u; float f; } hv; hv.u = v.u & 0xFFFF0000u;
    hi = (u16)(v.u >> 16);
    lo = rne_bf16(f - hv.f);
}
// monotone order-preserving f32 -> u32 key (total order; larger float => larger key)
__device__ __forceinline__ u32 f2key(float f) {
    union { float f; u32 u; } c; c.f = f;
    return (c.u & 0x80000000u) ? ~c.u : (c.u | 0x80000000u);
}

// Packed-plane layouts (bf16 bits, u16):
//   W plane:  idx = ((ct*32 + kb)*64 + lane)*8 + j   lane=(q<<4)|l16; col=ct*16+l16; k=kb*32+q*8+j
//   A plane:  idx = ((kb*4 + mt)*64 + lane)*8 + j    m=mt*16+l16;     k=kb*32+q*8+j

// ================== pack kernel: fp32 W (N x 1024 row-major) -> hi/lo planes ==================
__global__ __launch_bounds__(256) void pack_w_kernel(const float* __restrict__ W, int N,
                                                     u16* __restrict__ hi, u16* __restrict__ lo) {
    __shared__ float lds[16][260];
    const int ct = blockIdx.x, kg = blockIdx.y;      // 16 cols x 256 k per block
    const int t = threadIdx.x;
    {   // phase 1: coalesced global -> LDS
        const int r = t >> 4, c = t & 15;
        const int col = ct * 16 + r;
        const float* src = W + (size_t)col * HH + kg * 256;
#pragma unroll
        for (int i = 0; i < 4; ++i) {
            f32x4 v = (f32x4){0.f, 0.f, 0.f, 0.f};
            if (col < N) v = *(const f32x4*)(src + i * 64 + c * 4);
            int x = i * 64 + c * 4;
            lds[r][x + 0] = v[0]; lds[r][x + 1] = v[1];
            lds[r][x + 2] = v[2]; lds[r][x + 3] = v[3];
        }
    }
    __syncthreads();
#pragma unroll
    for (int rep = 0; rep < 2; ++rep) {
        int o = t + rep * 256;
        int tau = o >> 6, lam = o & 63;
        int q = lam >> 4, rr = lam & 15;
        int kl = tau * 32 + q * 8;
        bf16x8 hv, lv;
#pragma unroll
        for (int j = 0; j < 8; ++j) {
            u16 h, l; split2(lds[rr][kl + j], h, l);
            hv[j] = (short)h; lv[j] = (short)l;
        }
        size_t unit = (size_t)(ct * 32 + kg * 8 + tau) * 64 + lam;   // bf16x8 units
        ((bf16x8*)hi)[unit] = hv;
        ((bf16x8*)lo)[unit] = lv;
    }
}

// ================== split-K (x4 waves) packed bf16x3 GEMM body ==================
// Block: 256 threads = 4 waves; wave wv computes K-slice kb = wv*8 .. wv*8+7,
// partials staged in LDS (16 KB), wave wv reduces+stores output rows mt==wv.
__device__ __forceinline__ void gemm_sk_packed(
    const u16* __restrict__ Ahi, const u16* __restrict__ Alo,
    const u16* __restrict__ Bhi, const u16* __restrict__ Blo,
    const float* __restrict__ bias, float* __restrict__ C,
    int ct, int N, size_t ldc, float* lds)
{
    const int tid = threadIdx.x;
    const int wv = tid >> 6, lane = tid & 63;
    const int q = lane >> 4, l16 = lane & 15;

    const bf16x8* __restrict__ bh = (const bf16x8*)Bhi + (size_t)ct * 2048 + lane;
    const bf16x8* __restrict__ bl = (const bf16x8*)Blo + (size_t)ct * 2048 + lane;
    const bf16x8* __restrict__ ah = (const bf16x8*)Ahi + lane;
    const bf16x8* __restrict__ al = (const bf16x8*)Alo + lane;

    f32x4 acc[4];
#pragma unroll
    for (int mt = 0; mt < 4; ++mt) acc[mt] = (f32x4){0.f, 0.f, 0.f, 0.f};

#pragma unroll 2
    for (int kk = 0; kk < 8; ++kk) {
        const int kb = wv * 8 + kk;
        bf16x8 bhv = bh[kb * 64];
        bf16x8 blv = bl[kb * 64];
#pragma unroll
        for (int mt = 0; mt < 4; ++mt) {
            bf16x8 ahv = ah[(kb * 4 + mt) * 64];
            bf16x8 alv = al[(kb * 4 + mt) * 64];
            acc[mt] = __builtin_amdgcn_mfma_f32_16x16x32_bf16(ahv, bhv, acc[mt], 0, 0, 0);
            acc[mt] = __builtin_amdgcn_mfma_f32_16x16x32_bf16(alv, bhv, acc[mt], 0, 0, 0);
            acc[mt] = __builtin_amdgcn_mfma_f32_16x16x32_bf16(ahv, blv, acc[mt], 0, 0, 0);
        }
    }

#pragma unroll
    for (int mt = 0; mt < 4; ++mt)
        *(f32x4*)&lds[((wv * 4 + mt) * 64 + lane) * 4] = acc[mt];
    __syncthreads();
    {
        const int mt = wv;                  // wave wv owns output rows mt==wv
        f32x4 s0 = *(f32x4*)&lds[((0 * 4 + mt) * 64 + lane) * 4];
#pragma unroll
        for (int w2 = 1; w2 < 4; ++w2) {
            f32x4 v = *(f32x4*)&lds[((w2 * 4 + mt) * 64 + lane) * 4];
            s0[0] += v[0]; s0[1] += v[1]; s0[2] += v[2]; s0[3] += v[3];
        }
        const int col = ct * 16 + l16;
        if (col < N) {
            float bv = bias[col];
#pragma unroll
            for (int r = 0; r < 4; ++r)
                C[(size_t)(mt * 16 + q * 4 + r) * ldc + col] = s0[r] + bv;
        }
    }
}

// ================== split-K gates GEMM with A = relu(emb[xi]) read directly ==========
__device__ __forceinline__ void gemm_sk_emb(
    const float* __restrict__ emb, const u64* __restrict__ keys,
    const u16* __restrict__ Bhi, const u16* __restrict__ Blo,
    const float* __restrict__ bias, float* __restrict__ C, int ct, float* lds)
{
    const int tid = threadIdx.x;
    const int wv = tid >> 6, lane = tid & 63;
    const int q = lane >> 4, l16 = lane & 15;

    const bf16x8* __restrict__ bh = (const bf16x8*)Bhi + (size_t)ct * 2048 + lane;
    const bf16x8* __restrict__ bl = (const bf16x8*)Blo + (size_t)ct * 2048 + lane;

    const float* ea[4];
#pragma unroll
    for (int mt = 0; mt < 4; ++mt) {
        int xi = VV - (u32)(keys[mt * 16 + l16] & 0xFFFFFFFFull);
        ea[mt] = emb + (size_t)xi * HH + q * 8;
    }

    f32x4 acc[4];
#pragma unroll
    for (int mt = 0; mt < 4; ++mt) acc[mt] = (f32x4){0.f, 0.f, 0.f, 0.f};

#pragma unroll 2
    for (int kk = 0; kk < 8; ++kk) {
        const int kb = wv * 8 + kk;
        bf16x8 bhv = bh[kb * 64];
        bf16x8 blv = bl[kb * 64];
#pragma unroll
        for (int mt = 0; mt < 4; ++mt) {
            const float* ep = ea[mt] + kb * 32;
            f32x4 v0 = *(const f32x4*)(ep);
            f32x4 v1 = *(const f32x4*)(ep + 4);
            bf16x8 ahv, alv;
#pragma unroll
            for (int j = 0; j < 8; ++j) {
                float f = j < 4 ? v0[j] : v1[j - 4];
                f = f > 0.f ? f : 0.f;               // relu
                u16 h_, l_; split2(f, h_, l_);
                ahv[j] = (short)h_; alv[j] = (short)l_;
            }
            acc[mt] = __builtin_amdgcn_mfma_f32_16x16x32_bf16(ahv, bhv, acc[mt], 0, 0, 0);
            acc[mt] = __builtin_amdgcn_mfma_f32_16x16x32_bf16(alv, bhv, acc[mt], 0, 0, 0);
            acc[mt] = __builtin_amdgcn_mfma_f32_16x16x32_bf16(ahv, blv, acc[mt], 0, 0, 0);
        }
    }

#pragma unroll
    for (int mt = 0; mt < 4; ++mt)
        *(f32x4*)&lds[((wv * 4 + mt) * 64 + lane) * 4] = acc[mt];
    __syncthreads();
    {
        const int mt = wv;
        f32x4 s0 = *(f32x4*)&lds[((0 * 4 + mt) * 64 + lane) * 4];
#pragma unroll
        for (int w2 = 1; w2 < 4; ++w2) {
            f32x4 v = *(f32x4*)&lds[((w2 * 4 + mt) * 64 + lane) * 4];
            s0[0] += v[0]; s0[1] += v[1]; s0[2] += v[2]; s0[3] += v[3];
        }
        const int col = ct * 16 + l16;   // ct < NT_G => always valid
        float bv = bias[col];
#pragma unroll
        for (int r = 0; r < 4; ++r)
            C[(size_t)(mt * 16 + q * 4 + r) * GG + col] = s0[r] + bv;
    }
}

// packed A-plane u16 offset for element (b, k)
__device__ __forceinline__ size_t apack_off(int b, int k) {
    int kb = k >> 5, q = (k >> 3) & 3, joff = k & 7;
    int mt = b >> 4, l16 = b & 15;
    return ((size_t)(kb * 4 + mt) * 64 + (q * 16 + l16)) * 8 + joff;
}

// ================== init: h = enc[0]; keys[b] encodes target[:,0] ==================
__global__ void init_p_kernel(const int* __restrict__ target, const float* __restrict__ enc,
                              float* __restrict__ h, u16* __restrict__ h_hp, u16* __restrict__ h_lp,
                              u64* __restrict__ keys) {
    int b = blockIdx.x;
    if (threadIdx.x == 0) keys[b] = (u64)(u32)(VV - target[b * TT]);
    for (int k = threadIdx.x; k < HH; k += blockDim.x) {
        size_t po = apack_off(b, k);
        float hv = enc[b * HH + k];
        h[b * HH + k] = hv;
        u16 hh, hl; split2(hv, hh, hl);
        h_hp[po] = hh; h_lp[po] = hl;
    }
}

// ================== per-step GEMM kernels (split-K, 256 thr) ==================
__global__ __launch_bounds__(256) void gemm_gates_sk_kernel(
    const float* __restrict__ emb, const u64* __restrict__ keys,
    const u16* __restrict__ h_hp, const u16* __restrict__ h_lp,
    const u16* __restrict__ wih_hi, const u16* __restrict__ wih_lo,
    const u16* __restrict__ whh_hi, const u16* __restrict__ whh_lo,
    const float* __restrict__ b_ih, const float* __restrict__ b_hh,
    float* __restrict__ gi, float* __restrict__ gh)
{
    __shared__ float lds[4096];
    int ct = blockIdx.x;
    if (blockIdx.y == 0) gemm_sk_emb(emb, keys, wih_hi, wih_lo, b_ih, gi, ct, lds);
    else                 gemm_sk_packed(h_hp, h_lp, whh_hi, whh_lo, b_hh, gh, ct, GG, GG, lds);
}

__global__ __launch_bounds__(256) void gemm_logits_sk_kernel(
    const u16* __restrict__ h_hp, const u16* __restrict__ h_lp,
    const u16* __restrict__ wv_hi, const u16* __restrict__ wv_lo,
    const float* __restrict__ lin_b, float* __restrict__ out_logits)
{
    __shared__ float lds[4096];
    gemm_sk_packed(h_hp, h_lp, wv_hi, wv_lo, lin_b, out_logits,
                   blockIdx.x, VV, (size_t)TT * VV, lds);
}

// ================== standalone argmax-keys pass (no lse, no gather) ==================
__global__ __launch_bounds__(256) void argmax_keys_kernel(
    const float* __restrict__ out2_t, u64* __restrict__ keys)
{
    __shared__ u64 red[256];
    const int b = blockIdx.x, seg = blockIdx.y, tid = threadIdx.x;
    const float* row = out2_t + (size_t)b * (TT * (size_t)VV);
    const int SEG = (VV + 3) / 4;   // 12565
    const int lo = seg * SEG;
    const int hi = (lo + SEG) < VV ? (lo + SEG) : VV;
    u64 best = 0;
    for (int v = lo + tid; v < hi; v += 256) {
        u64 k = ((u64)f2key(row[v]) << 32) | (u32)(VV - v);   // smaller v wins ties
        best = best > k ? best : k;
    }
    red[tid] = best;
    __syncthreads();
    for (int off = 128; off > 0; off >>= 1) {
        if (tid < off) { u64 o = red[tid + off]; if (o > red[tid]) red[tid] = o; }
        __syncthreads();
    }
    if (tid == 0) atomicMax(&keys[b], red[0]);
}

// ================== GRU gating (packed h out) + argmax-key reset ==================
__global__ void gate_p_kernel(const float* __restrict__ gi, const float* __restrict__ gh,
                              float* __restrict__ h, u16* __restrict__ h_hp, u16* __restrict__ h_lp,
                              u64* __restrict__ keys) {
    if (blockIdx.x == 0 && threadIdx.x < BB) keys[threadIdx.x] = 0ull;  // reset before logits argmax
    int idx = blockIdx.x * blockDim.x + threadIdx.x;
    int b = idx >> 10, j = idx & 1023;
    float ir = gi[b * GG + j], iz = gi[b * GG + 1024 + j], in_ = gi[b * GG + 2048 + j];
    float hr = gh[b * GG + j], hz = gh[b * GG + 1024 + j], hn = gh[b * GG + 2048 + j];
    float r = 1.f / (1.f + expf(-(ir + hr)));
    float z = 1.f / (1.f + expf(-(iz + hz)));
    float n = tanhf(in_ + r * hn);
    float hold = h[b * HH + j];
    float hnew = (1.f - z) * n + z * hold;
    h[b * HH + j] = hnew;
    u16 hh, hl; split2(hnew, hh, hl);
    size_t po = apack_off(b, j);
    h_hp[po] = hh; h_lp[po] = hl;
}

// ================== final: lse per row + log_softmax write ==================
__global__ __launch_bounds__(256) void lse_logsoftmax_kernel(
    const float* __restrict__ out2, float* __restrict__ out1)
{
    __shared__ float sm[256], ss[256];
    int row = blockIdx.x, tid = threadIdx.x;
    const float* src = out2 + (size_t)row * VV;
    float* dst = out1 + (size_t)row * VV;

    float m = -INFINITY, s = 0.f;
    for (int v = tid; v < VV; v += 256) {
        float x = src[v];
        if (x > m) { s = s * expf(m - x) + 1.f; m = x; }
        else       { s += expf(x - m); }
    }
    sm[tid] = m; ss[tid] = s;
    __syncthreads();
    for (int off = 128; off > 0; off >>= 1) {
        if (tid < off) {
            float m1 = sm[tid], s1 = ss[tid];
            float m2 = sm[tid + off], s2 = ss[tid + off];
            float mn = fmaxf(m1, m2);
            sm[tid] = mn; ss[tid] = s1 * expf(m1 - mn) + s2 * expf(m2 - mn);
        }
        __syncthreads();
    }
    float lse = sm[0] + logf(ss[0]);

    const int NF4 = VV / 4;   // 12564  (row re-read is L2/L3-warm)
    for (int i = tid; i < NF4; i += 256) {
        f32x4 v = *(const f32x4*)(src + i * 4);
        v[0] -= lse; v[1] -= lse; v[2] -= lse; v[3] -= lse;
        *(f32x4*)(dst + i * 4) = v;
    }
    if (tid == 0) dst[VV - 1] = src[VV - 1] - lse;
}

// ================== final log_softmax (fallback path only) ==================
__global__ void logsoftmax_kernel(const float* __restrict__ out2, const float* __restrict__ row_lse,
                                  float* __restrict__ out1) {
    int row = blockIdx.x;
    float lse = row_lse[row];
    const float* src = out2 + (size_t)row * VV;
    float* dst = out1 + (size_t)row * VV;
    const int NF4 = VV / 4;   // 12564
    for (int i = threadIdx.x; i < NF4; i += blockDim.x) {
        f32x4 v = *(const f32x4*)(src + i * 4);
        v[0] -= lse; v[1] -= lse; v[2] -= lse; v[3] -= lse;
        *(f32x4*)(dst + i * 4) = v;
    }
    if (threadIdx.x == 0) dst[VV - 1] = src[VV - 1] - lse;
}

// ======================================================================
// =================== round-1 fallback path (unpacked) =================
// ======================================================================
__global__ void init_kernel_fb(const int* __restrict__ target, const float* __restrict__ enc,
                               const float* __restrict__ emb,
                               float* __restrict__ h, u16* __restrict__ h_hi, u16* __restrict__ h_lo,
                               u16* __restrict__ e_hi, u16* __restrict__ e_lo) {
    int b = blockIdx.x;
    int x0 = target[b * TT];
    for (int k = threadIdx.x; k < HH; k += blockDim.x) {
        float hv = enc[b * HH + k];
        h[b * HH + k] = hv;
        u16 hh, hl; split2(hv, hh, hl);
        h_hi[b * HH + k] = hh; h_lo[b * HH + k] = hl;
        float e = emb[(size_t)x0 * HH + k];
        e = e > 0.f ? e : 0.f;
        u16 eh, el; split2(e, eh, el);
        e_hi[b * HH + k] = eh; e_lo[b * HH + k] = el;
    }
}

__device__ __forceinline__ void gemm_body_fb(
    const u16* __restrict__ Ahi, const u16* __restrict__ Alo,
    const float* __restrict__ W, const float* __restrict__ bias,
    float* __restrict__ C, int N, int ldc)
{
    const int wave = threadIdx.x >> 6;
    const int lane = threadIdx.x & 63;
    const int quad = lane >> 4;
    const int l16  = lane & 15;
    const int col  = blockIdx.x * 64 + wave * 16 + l16;
    const int colc = col < N ? col : N - 1;
    const float* __restrict__ Brow = W + (size_t)colc * HH;
    const int koff = quad * 8;
    f32x4 acc[4];
#pragma unroll
    for (int mt = 0; mt < 4; ++mt) acc[mt] = (f32x4){0.f, 0.f, 0.f, 0.f};
    for (int kb = 0; kb < HH; kb += 32) {
        const float* bp = Brow + kb + koff;
        f32x4 bv0 = *(const f32x4*)(bp);
        f32x4 bv1 = *(const f32x4*)(bp + 4);
        bf16x8 bhi, blo;
#pragma unroll
        for (int j = 0; j < 8; ++j) {
            float f = j < 4 ? bv0[j] : bv1[j - 4];
            union { float f; u32 u; } c; c.f = f;
            union { u32 u; float f; } hf; hf.u = c.u & 0xFFFF0000u;
            bhi[j] = (short)(c.u >> 16);
            blo[j] = (short)rne_bf16(f - hf.f);
        }
#pragma unroll
        for (int mt = 0; mt < 4; ++mt) {
            const size_t aoff = (size_t)(mt * 16 + l16) * HH + kb + koff;
            bf16x8 ahi = *(const bf16x8*)(Ahi + aoff);
            bf16x8 alo = *(const bf16x8*)(Alo + aoff);
            acc[mt] = __builtin_amdgcn_mfma_f32_16x16x32_bf16(ahi, bhi, acc[mt], 0, 0, 0);
            acc[mt] = __builtin_amdgcn_mfma_f32_16x16x32_bf16(alo, bhi, acc[mt], 0, 0, 0);
            acc[mt] = __builtin_amdgcn_mfma_f32_16x16x32_bf16(ahi, blo, acc[mt], 0, 0, 0);
        }
    }
    if (col < N) {
        float bv = bias[col];
#pragma unroll
        for (int mt = 0; mt < 4; ++mt)
#pragma unroll
            for (int r = 0; r < 4; ++r)
                C[(size_t)(mt * 16 + quad * 4 + r) * ldc + col] = acc[mt][r] + bv;
    }
}

__global__ __launch_bounds__(256) void gemm_gates_kernel_fb(
    const u16* __restrict__ e_hi, const u16* __restrict__ e_lo,
    const u16* __restrict__ h_hi, const u16* __restrict__ h_lo,
    const float* __restrict__ w_ih, const float* __restrict__ w_hh,
    const float* __restrict__ b_ih, const float* __restrict__ b_hh,
    float* __restrict__ gi, float* __restrict__ gh)
{
    if (blockIdx.y == 0) gemm_body_fb(e_hi, e_lo, w_ih, b_ih, gi, GG, GG);
    else                 gemm_body_fb(h_hi, h_lo, w_hh, b_hh, gh, GG, GG);
}

__global__ __launch_bounds__(256) void gemm_logits_kernel_fb(
    const u16* __restrict__ h_hi, const u16* __restrict__ h_lo,
    const float* __restrict__ lin_w, const float* __restrict__ lin_b,
    float* __restrict__ out_logits)
{
    gemm_body_fb(h_hi, h_lo, lin_w, lin_b, out_logits, VV, TT * VV);
}

__global__ void gate_kernel_fb(const float* __restrict__ gi, const float* __restrict__ gh,
                               float* __restrict__ h, u16* __restrict__ h_hi, u16* __restrict__ h_lo) {
    int idx = blockIdx.x * blockDim.x + threadIdx.x;
    int b = idx >> 10, j = idx & 1023;
    float ir = gi[b * GG + j], iz = gi[b * GG + 1024 + j], in_ = gi[b * GG + 2048 + j];
    float hr = gh[b * GG + j], hz = gh[b * GG + 1024 + j], hn = gh[b * GG + 2048 + j];
    float r = 1.f / (1.f + expf(-(ir + hr)));
    float z = 1.f / (1.f + expf(-(iz + hz)));
    float n = tanhf(in_ + r * hn);
    float hold = h[b * HH + j];
    float hnew = (1.f - z) * n + z * hold;
    h[b * HH + j] = hnew;
    u16 hh, hl; split2(hnew, hh, hl);
    h_hi[b * HH + j] = hh; h_lo[b * HH + j] = hl;
}

__global__ __launch_bounds__(256) void argmax_kernel_fb(
    const float* __restrict__ logits_t, const float* __restrict__ emb,
    int t, float* __restrict__ row_lse, u16* __restrict__ e_hi, u16* __restrict__ e_lo)
{
    __shared__ float sm[256], ss[256];
    __shared__ int sbi[256];
    int b = blockIdx.x, tid = threadIdx.x;
    const float* row = logits_t + (size_t)b * (TT * (size_t)VV);
    float m = -INFINITY, s = 0.f; int bi = 0x7fffffff;
    for (int v = tid; v < VV; v += 256) {
        float x = row[v];
        if (x > m) { s = s * expf(m - x) + 1.f; m = x; bi = v; }
        else       { s += expf(x - m); }
    }
    sm[tid] = m; ss[tid] = s; sbi[tid] = bi;
    __syncthreads();
    for (int off = 128; off > 0; off >>= 1) {
        if (tid < off) {
            float m1 = sm[tid], s1 = ss[tid]; int b1 = sbi[tid];
            float m2 = sm[tid + off], s2 = ss[tid + off]; int b2 = sbi[tid + off];
            float mn = fmaxf(m1, m2);
            float sn = s1 * expf(m1 - mn) + s2 * expf(m2 - mn);
            int bn = (m1 > m2) ? b1 : (m2 > m1) ? b2 : min(b1, b2);
            sm[tid] = mn; ss[tid] = sn; sbi[tid] = bn;
        }
        __syncthreads();
    }
    if (tid == 0) row_lse[b * TT + t] = sm[0] + logf(ss[0]);
    int xi = sbi[0];
    __syncthreads();
    for (int k = tid; k < HH; k += 256) {
        float e = emb[(size_t)xi * HH + k];
        e = e > 0.f ? e : 0.f;
        u16 eh, el; split2(e, eh, el);
        e_hi[b * HH + k] = eh; e_lo[b * HH + k] = el;
    }
}

// ======================================================================
extern "C" void kernel_launch(void* const* d_in, const int* in_sizes, int n_in,
                              void* d_out, int out_size, void* d_ws, size_t ws_size,
                              hipStream_t stream) {
    const int*   target = (const int*)  d_in[0];
    const float* enc    = (const float*)d_in[1];
    const float* emb    = (const float*)d_in[2];
    const float* w_ih   = (const float*)d_in[3];
    const float* w_hh   = (const float*)d_in[4];
    const float* b_ih   = (const float*)d_in[5];
    const float* b_hh   = (const float*)d_in[6];
    const float* lin_w  = (const float*)d_in[7];
    const float* lin_b  = (const float*)d_in[8];
    float* out1 = (float*)d_out;                       // log_probs  (B,T,V)
    float* out2 = out1 + (size_t)BB * TT * VV;         // decoder_logits (B,T,V)

    const size_t SZ_WV = (size_t)NT_V * 16384;         // u16 per V plane
    const size_t SZ_WG = (size_t)NT_G * 16384;         // u16 per gates plane
    const size_t need = 2 * SZ_WV * 2 + 4 * SZ_WG * 2  // packed W planes (bytes)
                      + BB * HH * 4                    // h
                      + 2 * BB * HH * 2                // packed h planes
                      + 2 * BB * GG * 4                // gi, gh
                      + BB * 8 + 1024;                 // keys + slack

    if (ws_size >= need) {
        char* w = (char*)d_ws;
        u16* wv_hi = (u16*)w;  w += SZ_WV * 2;
        u16* wv_lo = (u16*)w;  w += SZ_WV * 2;
        u16* wih_hi = (u16*)w; w += SZ_WG * 2;
        u16* wih_lo = (u16*)w; w += SZ_WG * 2;
        u16* whh_hi = (u16*)w; w += SZ_WG * 2;
        u16* whh_lo = (u16*)w; w += SZ_WG * 2;
        float* h   = (float*)w; w += BB * HH * 4;
        u16* h_hp  = (u16*)w;  w += BB * HH * 2;
        u16* h_lp  = (u16*)w;  w += BB * HH * 2;
        float* gi  = (float*)w; w += BB * GG * 4;
        float* gh  = (float*)w; w += BB * GG * 4;
        u64* keys  = (u64*)w;

        // one-time packs
        pack_w_kernel<<<dim3(NT_V, 4), 256, 0, stream>>>(lin_w, VV, wv_hi, wv_lo);
        pack_w_kernel<<<dim3(NT_G, 4), 256, 0, stream>>>(w_ih, GG, wih_hi, wih_lo);
        pack_w_kernel<<<dim3(NT_G, 4), 256, 0, stream>>>(w_hh, GG, whh_hi, whh_lo);
        init_p_kernel<<<BB, 256, 0, stream>>>(target, enc, h, h_hp, h_lp, keys);

        for (int t = 0; t < TT; ++t) {
            // gates GEMM (split-K x4): y==0 reads relu(emb[xi]) via keys; y==1 reads packed h
            gemm_gates_sk_kernel<<<dim3(NT_G, 2), 256, 0, stream>>>(
                emb, keys, h_hp, h_lp, wih_hi, wih_lo, whh_hi, whh_lo, b_ih, b_hh, gi, gh);
            // GRU gate + pack h; resets keys for this step's argmax
            gate_p_kernel<<<(BB * HH) / 256, 256, 0, stream>>>(gi, gh, h, h_hp, h_lp, keys);
            // logits GEMM (split-K x4, one 16-col tile per block)
            gemm_logits_sk_kernel<<<NT_V, 256, 0, stream>>>(
                h_hp, h_lp, wv_hi, wv_lo, lin_b, out2 + (size_t)t * VV);
            // standalone argmax pass (keys only; lse deferred, gather fused into gates)
            argmax_keys_kernel<<<dim3(BB, 4), 256, 0, stream>>>(out2 + (size_t)t * VV, keys);
        }
        lse_logsoftmax_kernel<<<BB * TT, 256, 0, stream>>>(out2, out1);
    } else {
        // -------- fallback: round-1 path (~3.6 MB ws) --------
        char* w = (char*)d_ws;
        float* h    = (float*)w;            w += BB * HH * 4;
        u16*   h_hi = (u16*)w;              w += BB * HH * 2;
        u16*   h_lo = (u16*)w;              w += BB * HH * 2;
        u16*   e_hi = (u16*)w;              w += BB * HH * 2;
        u16*   e_lo = (u16*)w;              w += BB * HH * 2;
        float* gi   = (float*)w;            w += BB * GG * 4;
        float* gh   = (float*)w;            w += BB * GG * 4;
        float* row_lse = (float*)w;

        init_kernel_fb<<<BB, 256, 0, stream>>>(target, enc, emb, h, h_hi, h_lo, e_hi, e_lo);
        const int NB_G = GG / 64;
        const int NB_V = (VV + 63) / 64;
        for (int t = 0; t < TT; ++t) {
            gemm_gates_kernel_fb<<<dim3(NB_G, 2), 256, 0, stream>>>(
                e_hi, e_lo, h_hi, h_lo, w_ih, w_hh, b_ih, b_hh, gi, gh);
            gate_kernel_fb<<<(BB * HH) / 256, 256, 0, stream>>>(gi, gh, h, h_hi, h_lo);
            gemm_logits_kernel_fb<<<NB_V, 256, 0, stream>>>(h_hi, h_lo, lin_w, lin_b,
                                                            out2 + (size_t)t * VV);
            argmax_kernel_fb<<<BB, 256, 0, stream>>>(out2 + (size_t)t * VV, emb, t,
                                                     row_lse, e_hi, e_lo);
        }
        logsoftmax_kernel<<<BB * TT, 256, 0, stream>>>(out2, row_lse, out1);
    }
}